// Round 4
// baseline (341.115 us; speedup 1.0000x reference)
//
#include <hip/hip_runtime.h>
#include <hip/hip_fp16.h>
#include <math.h>

#define N_NODES  50000
#define N_HEDGES 10000
#define N_MEMB   800000
#define KIN      256
#define CH       256
#define HEADS    4
#define HS       4      // hedge sub-queues per hyperedge (selected by member%4)
#define HCAP_S   64     // per-sub-list capacity (mean ~20, Poisson tail safe)
#define NS       2      // node sub-queues
#define NCAP_S   32     // per-sub-list capacity (mean ~8)
#define GR       16     // gemm rows per block

#define M4          (N_MEMB / 4)                 // 200000 int4 members
#define SCAT_BLOCKS ((M4 + 255) / 256)           // 782
#define CVT_THREADS (N_NODES * KIN / 4 / 2)      // 1.6M threads, 2 float4 each
#define CVT_BLOCKS  (CVT_THREADS / 256)          // 6250
#define S1_BLOCKS   (N_HEDGES / 4)               // 2500

__device__ inline float2 h2f(unsigned u) {
    __half2 h = __builtin_bit_cast(__half2, u);
    return __half22float2(h);
}
__device__ inline unsigned f2h(float a, float b) {
    return __builtin_bit_cast(unsigned, __floats2half2_rn(a, b));
}
__device__ inline float4 u2tof4(uint2 u) {
    float2 lo = h2f(u.x), hi = h2f(u.y);
    return make_float4(lo.x, lo.y, hi.x, hi.y);
}

// ---------- K1: hedge-CSR scatter (sub-queued) || x fp32->fp16 convert ----------
__global__ void k_hscatter_cvt(const int4* __restrict__ ni4, const int4* __restrict__ hi4,
                               int* __restrict__ hcur, int* __restrict__ hmem,
                               const float4* __restrict__ x4, uint2* __restrict__ x16) {
    int bid = blockIdx.x, tid = threadIdx.x;
    if (bid < SCAT_BLOCKS) {
        int m4 = bid * 256 + tid;
        if (m4 < M4) {
            int4 e = hi4[m4]; int4 n = ni4[m4];
            int p;
            p = atomicAdd(&hcur[e.x * HS + 0], 1); if (p < HCAP_S) hmem[((size_t)e.x * HS + 0) * HCAP_S + p] = n.x;
            p = atomicAdd(&hcur[e.y * HS + 1], 1); if (p < HCAP_S) hmem[((size_t)e.y * HS + 1) * HCAP_S + p] = n.y;
            p = atomicAdd(&hcur[e.z * HS + 2], 1); if (p < HCAP_S) hmem[((size_t)e.z * HS + 2) * HCAP_S + p] = n.z;
            p = atomicAdd(&hcur[e.w * HS + 3], 1); if (p < HCAP_S) hmem[((size_t)e.w * HS + 3) * HCAP_S + p] = n.w;
        }
    } else {
        int i = (bid - SCAT_BLOCKS) * 256 + tid;
        #pragma unroll
        for (int r = 0; r < 2; r++) {
            int idx = i + r * CVT_THREADS;
            float4 v = x4[idx];
            uint2 u; u.x = f2h(v.x, v.y); u.y = f2h(v.z, v.w);
            x16[idx] = u;
        }
    }
}

// ---------- K2: node-CSR scatter (sub-queued) || stage1 mean-gather ----------
__global__ void k_nscatter_stage1(const int4* __restrict__ ni4, const int4* __restrict__ hi4,
                                  int* __restrict__ ncur, int* __restrict__ nhedge,
                                  const int* __restrict__ hcur, const int* __restrict__ hmem,
                                  const uint2* __restrict__ x16, uint2* __restrict__ hx) {
    int bid = blockIdx.x, tid = threadIdx.x;
    if (bid < SCAT_BLOCKS) {
        int m4 = bid * 256 + tid;
        if (m4 < M4) {
            int4 e = hi4[m4]; int4 n = ni4[m4];
            int q;
            q = atomicAdd(&ncur[n.x * NS + 0], 1); if (q < NCAP_S) nhedge[((size_t)n.x * NS + 0) * NCAP_S + q] = e.x;
            q = atomicAdd(&ncur[n.y * NS + 1], 1); if (q < NCAP_S) nhedge[((size_t)n.y * NS + 1) * NCAP_S + q] = e.y;
            q = atomicAdd(&ncur[n.z * NS + 0], 1); if (q < NCAP_S) nhedge[((size_t)n.z * NS + 0) * NCAP_S + q] = e.z;
            q = atomicAdd(&ncur[n.w * NS + 1], 1); if (q < NCAP_S) nhedge[((size_t)n.w * NS + 1) * NCAP_S + q] = e.w;
        }
    } else {
        int b = bid - SCAT_BLOCKS;           // 0..S1_BLOCKS-1
        int w = tid >> 6, lt = tid & 63;     // wave per hyperedge, lane owns 4 channels
        int e = b * 4 + w;
        int c0 = hcur[e * HS + 0], c1 = hcur[e * HS + 1];
        int c2 = hcur[e * HS + 2], c3 = hcur[e * HS + 3];
        int degR = c0 + c1 + c2 + c3;        // true degree (matches reference divisor)
        int d0 = min(c0, HCAP_S), d1 = min(c1, HCAP_S);
        int d2 = min(c2, HCAP_S), d3 = min(c3, HCAP_S);
        size_t b0 = ((size_t)e * HS + 0) * HCAP_S, b1 = ((size_t)e * HS + 1) * HCAP_S;
        size_t b2 = ((size_t)e * HS + 2) * HCAP_S, b3 = ((size_t)e * HS + 3) * HCAP_S;
        int dmax = max(max(d0, d1), max(d2, d3));
        float a0x=0,a0y=0,a0z=0,a0w=0, a1x=0,a1y=0,a1z=0,a1w=0;
        float a2x=0,a2y=0,a2z=0,a2w=0, a3x=0,a3y=0,a3z=0,a3w=0;
        for (int i = 0; i < dmax; i++) {
            if (i < d0) { int n = hmem[b0 + i]; float4 f = u2tof4(x16[(size_t)n * 64 + lt]);
                          a0x += f.x; a0y += f.y; a0z += f.z; a0w += f.w; }
            if (i < d1) { int n = hmem[b1 + i]; float4 f = u2tof4(x16[(size_t)n * 64 + lt]);
                          a1x += f.x; a1y += f.y; a1z += f.z; a1w += f.w; }
            if (i < d2) { int n = hmem[b2 + i]; float4 f = u2tof4(x16[(size_t)n * 64 + lt]);
                          a2x += f.x; a2y += f.y; a2z += f.z; a2w += f.w; }
            if (i < d3) { int n = hmem[b3 + i]; float4 f = u2tof4(x16[(size_t)n * 64 + lt]);
                          a3x += f.x; a3y += f.y; a3z += f.z; a3w += f.w; }
        }
        float sx = (a0x + a1x) + (a2x + a3x);
        float sy = (a0y + a1y) + (a2y + a3y);
        float sz = (a0z + a1z) + (a2z + a3z);
        float sw = (a0w + a1w) + (a2w + a3w);
        float inv = degR > 0 ? 1.0f / (float)degR : 0.0f;
        uint2 o; o.x = f2h(sx * inv, sy * inv); o.y = f2h(sz * inv, sw * inv);
        hx[(size_t)e * 64 + lt] = o;
    }
}

// ---------- K3: he = hx @ W fused with alpha = leaky_relu(<he, att>, 0.2) ----------
__global__ void k_gemm_alpha(const uint2* __restrict__ hx, const float* __restrict__ W,
                             const float* __restrict__ att, __half* __restrict__ he,
                             float* __restrict__ alpha) {
    __shared__ float xs[GR][KIN];
    int tid = threadIdx.x;
    int e0 = blockIdx.x * GR;
    #pragma unroll
    for (int jj = 0; jj < GR * 64 / 256; jj++) {
        int f = jj * 256 + tid;
        int r = f >> 6, k4 = f & 63;
        float4 v = u2tof4(hx[(size_t)(e0 + r) * 64 + k4]);
        *(float4*)&xs[r][k4 * 4] = v;
    }
    __syncthreads();
    float acc[GR];
    #pragma unroll
    for (int r = 0; r < GR; r++) acc[r] = 0.f;
    int c = tid;
    for (int k = 0; k < KIN; k++) {
        float wv = W[(size_t)k * CH + c];
        #pragma unroll
        for (int r = 0; r < GR; r++) acc[r] += xs[r][k] * wv;
    }
    #pragma unroll
    for (int r = 0; r < GR; r++)
        he[(size_t)(e0 + r) * CH + c] = __float2half_rn(acc[r]);
    float av = att[c];
    int lane = tid & 63, h = tid >> 6;  // wave == head (64 consecutive channels)
    #pragma unroll
    for (int r = 0; r < GR; r++) {
        float p = acc[r] * av;
        #pragma unroll
        for (int d = 32; d >= 1; d >>= 1) p += __shfl_xor(p, d, 64);
        if (lane == 0) alpha[(e0 + r) * HEADS + h] = p > 0.f ? p : 0.2f * p;
    }
}

// ---------- K4: stage2 per-node softmax + weighted gather-sum ----------
__global__ void k_stage2(const uint2* __restrict__ he, const float4* __restrict__ alpha4,
                         const int* __restrict__ ncur, const int* __restrict__ nhedge,
                         float4* __restrict__ out) {
    __shared__ int   nh[4][64];
    __shared__ float wl[4][64 * 4];
    int tid = threadIdx.x;
    int w = tid >> 6, lt = tid & 63;
    int n = blockIdx.x * 4 + w;
    int c0 = ncur[n * NS + 0], c1 = ncur[n * NS + 1];
    int d0 = min(c0, NCAP_S), d1 = min(c1, NCAP_S);
    int deg = d0 + d1;
    float4 aj = make_float4(-INFINITY, -INFINITY, -INFINITY, -INFINITY);
    int ej = 0;
    if (lt < deg) {
        ej = (lt < d0) ? nhedge[((size_t)n * NS + 0) * NCAP_S + lt]
                       : nhedge[((size_t)n * NS + 1) * NCAP_S + (lt - d0)];
        aj = alpha4[ej];
    }
    float4 mx = aj;
    #pragma unroll
    for (int d = 32; d >= 1; d >>= 1) {
        mx.x = fmaxf(mx.x, __shfl_xor(mx.x, d, 64));
        mx.y = fmaxf(mx.y, __shfl_xor(mx.y, d, 64));
        mx.z = fmaxf(mx.z, __shfl_xor(mx.z, d, 64));
        mx.w = fmaxf(mx.w, __shfl_xor(mx.w, d, 64));
    }
    float4 w4 = make_float4(0.f, 0.f, 0.f, 0.f);
    if (lt < deg) {
        w4.x = __expf(aj.x - mx.x); w4.y = __expf(aj.y - mx.y);
        w4.z = __expf(aj.z - mx.z); w4.w = __expf(aj.w - mx.w);
        nh[w][lt] = ej;
        *(float4*)&wl[w][lt * 4] = w4;
    }
    float4 dn = w4;
    #pragma unroll
    for (int d = 32; d >= 1; d >>= 1) {
        dn.x += __shfl_xor(dn.x, d, 64);
        dn.y += __shfl_xor(dn.y, d, 64);
        dn.z += __shfl_xor(dn.z, d, 64);
        dn.w += __shfl_xor(dn.w, d, 64);
    }
    int h = lt >> 4;  // lane owns channels 4lt..4lt+3 -> head
    float den = h < 2 ? (h == 0 ? dn.x : dn.y) : (h == 2 ? dn.z : dn.w);
    float acx = 0.f, acy = 0.f, acz = 0.f, acw = 0.f;
    if (deg > 0) {
        int j = 0;
        for (; j + 2 <= deg; j += 2) {
            int ea = nh[w][j], eb = nh[w][j + 1];
            float wa = wl[w][j * 4 + h], wb = wl[w][j * 4 + 4 + h];
            float4 fa = u2tof4(he[(size_t)ea * 64 + lt]);
            float4 fb = u2tof4(he[(size_t)eb * 64 + lt]);
            acx += wa * fa.x + wb * fb.x;
            acy += wa * fa.y + wb * fb.y;
            acz += wa * fa.z + wb * fb.z;
            acw += wa * fa.w + wb * fb.w;
        }
        if (j < deg) {
            int ea = nh[w][j];
            float wa = wl[w][j * 4 + h];
            float4 fa = u2tof4(he[(size_t)ea * 64 + lt]);
            acx += wa * fa.x; acy += wa * fa.y; acz += wa * fa.z; acw += wa * fa.w;
        }
        float inv = 1.0f / den;
        acx *= inv; acy *= inv; acz *= inv; acw *= inv;
    }
    out[(size_t)n * 64 + lt] = make_float4(acx, acy, acz, acw);
}

extern "C" void kernel_launch(void* const* d_in, const int* in_sizes, int n_in,
                              void* d_out, int out_size, void* d_ws, size_t ws_size,
                              hipStream_t stream) {
    const float* x        = (const float*)d_in[0];
    const float* W        = (const float*)d_in[1];
    const float* att      = (const float*)d_in[2];
    const int*   node_idx = (const int*)d_in[3];
    const int*   hedge_idx= (const int*)d_in[4];
    float4* out4 = (float4*)d_out;

    char* ws = (char*)d_ws;
    size_t o = 0;
    auto alloc = [&](size_t b) { size_t r = o; o += (b + 255) & ~(size_t)255; return r; };
    uint2* hx    = (uint2*)(ws + alloc(sizeof(__half) * (size_t)N_HEDGES * KIN));     // 5.12 MB
    float* alpha = (float*)(ws + alloc(sizeof(float) * (size_t)N_HEDGES * HEADS));    // 160 KB
    int*   hcur  = (int*)(ws + alloc(sizeof(int) * (size_t)N_HEDGES * HS));           // 160 KB
    int*   ncur  = (int*)(ws + alloc(sizeof(int) * (size_t)N_NODES * NS));            // 400 KB
    // hmem sub-lists are dead after stage1; he (gemm output, 5.12MB) reuses the region
    size_t hmem_off = alloc(sizeof(int) * (size_t)N_HEDGES * HS * HCAP_S);            // 10.24 MB
    int*    hmem = (int*)(ws + hmem_off);
    __half* he   = (__half*)(ws + hmem_off);
    int*   nhedge = (int*)(ws + alloc(sizeof(int) * (size_t)N_NODES * NS * NCAP_S));  // 12.8 MB
    // x16 lives in d_out (51.2 MB): consumed by stage1 (K2), overwritten by stage2 (K4)
    uint2* x16 = (uint2*)d_out;

    hipMemsetAsync(hcur, 0, sizeof(int) * (size_t)N_HEDGES * HS, stream);
    hipMemsetAsync(ncur, 0, sizeof(int) * (size_t)N_NODES * NS, stream);
    k_hscatter_cvt<<<SCAT_BLOCKS + CVT_BLOCKS, 256, 0, stream>>>(
        (const int4*)node_idx, (const int4*)hedge_idx, hcur, hmem, (const float4*)x, x16);
    k_nscatter_stage1<<<SCAT_BLOCKS + S1_BLOCKS, 256, 0, stream>>>(
        (const int4*)node_idx, (const int4*)hedge_idx, ncur, nhedge, hcur, hmem, x16, hx);
    k_gemm_alpha<<<N_HEDGES / GR, 256, 0, stream>>>(hx, W, att, he, alpha);
    k_stage2<<<N_NODES / 4, 256, 0, stream>>>((const uint2*)he, (const float4*)alpha,
                                              ncur, nhedge, out4);
}

// Round 5
// 286.016 us; speedup vs baseline: 1.1926x; 1.1926x over previous
//
#include <hip/hip_runtime.h>
#include <hip/hip_fp16.h>
#include <math.h>

#define N_NODES  50000
#define N_HEDGES 10000
#define N_MEMB   800000
#define KIN      256
#define CH       256
#define HEADS    4
#define HS       4      // hedge sub-queues per hyperedge (selected by member%4)
#define HCAP_S   64     // per-sub-list capacity (mean ~20, max ~40)
#define NS       2      // node sub-queues
#define NCAP_S   32     // per-sub-list capacity (mean ~8, max ~22)
#define GR       16     // gemm rows per block

#define M4          (N_MEMB / 4)                 // 200000 int4 members
#define SCAT_BLOCKS ((M4 + 255) / 256)           // 782
#define CVT_THREADS (N_NODES * KIN / 4 / 2)      // 1.6M threads, 2 float4 each
#define CVT_BLOCKS  (CVT_THREADS / 256)          // 6250
#define WCVT_BLOCKS (KIN * CH / 8 / 256)         // 32
#define S1_BLOCKS   (N_HEDGES / 4)               // 2500

__device__ inline float2 h2f(unsigned u) {
    __half2 h = __builtin_bit_cast(__half2, u);
    return __half22float2(h);
}
__device__ inline unsigned f2h(float a, float b) {
    return __builtin_bit_cast(unsigned, __floats2half2_rn(a, b));
}
__device__ inline float4 u2tof4(uint2 u) {
    float2 lo = h2f(u.x), hi = h2f(u.y);
    return make_float4(lo.x, lo.y, hi.x, hi.y);
}
__device__ inline void acc4(float4& a, float4 f) {
    a.x += f.x; a.y += f.y; a.z += f.z; a.w += f.w;
}

// ---------- K1: hedge-CSR scatter || x fp32->fp16 || W fp32->fp16 ----------
__global__ void k_hscatter_cvt(const int4* __restrict__ ni4, const int4* __restrict__ hi4,
                               int* __restrict__ hcur, int* __restrict__ hmem,
                               const float4* __restrict__ x4, uint2* __restrict__ x16,
                               const float4* __restrict__ Wf, uint2* __restrict__ W16) {
    int bid = blockIdx.x, tid = threadIdx.x;
    if (bid < SCAT_BLOCKS) {
        int m4 = bid * 256 + tid;
        if (m4 < M4) {
            int4 e = hi4[m4]; int4 n = ni4[m4];
            int p;
            p = atomicAdd(&hcur[e.x * HS + 0], 1); if (p < HCAP_S) hmem[((size_t)e.x * HS + 0) * HCAP_S + p] = n.x;
            p = atomicAdd(&hcur[e.y * HS + 1], 1); if (p < HCAP_S) hmem[((size_t)e.y * HS + 1) * HCAP_S + p] = n.y;
            p = atomicAdd(&hcur[e.z * HS + 2], 1); if (p < HCAP_S) hmem[((size_t)e.z * HS + 2) * HCAP_S + p] = n.z;
            p = atomicAdd(&hcur[e.w * HS + 3], 1); if (p < HCAP_S) hmem[((size_t)e.w * HS + 3) * HCAP_S + p] = n.w;
        }
    } else if (bid < SCAT_BLOCKS + CVT_BLOCKS) {
        int i = (bid - SCAT_BLOCKS) * 256 + tid;
        #pragma unroll
        for (int r = 0; r < 2; r++) {
            int idx = i + r * CVT_THREADS;
            float4 v = x4[idx];
            uint2 u; u.x = f2h(v.x, v.y); u.y = f2h(v.z, v.w);
            x16[idx] = u;
        }
    } else {
        int i = (bid - SCAT_BLOCKS - CVT_BLOCKS) * 256 + tid;   // 0..8191, 8 floats each
        #pragma unroll
        for (int r = 0; r < 2; r++) {
            float4 v = Wf[i * 2 + r];
            uint2 u; u.x = f2h(v.x, v.y); u.y = f2h(v.z, v.w);
            W16[i * 2 + r] = u;
        }
    }
}

// ---------- K2: node-CSR scatter || stage1 mean-gather (LDS-staged indices) ----------
__global__ void k_nscatter_stage1(const int4* __restrict__ ni4, const int4* __restrict__ hi4,
                                  int* __restrict__ ncur, int* __restrict__ nhedge,
                                  const int* __restrict__ hcur, const int* __restrict__ hmem,
                                  const uint2* __restrict__ x16, uint2* __restrict__ hx) {
    int bid = blockIdx.x, tid = threadIdx.x;
    if (bid < SCAT_BLOCKS) {
        int m4 = bid * 256 + tid;
        if (m4 < M4) {
            int4 e = hi4[m4]; int4 n = ni4[m4];
            int q;
            q = atomicAdd(&ncur[n.x * NS + 0], 1); if (q < NCAP_S) nhedge[((size_t)n.x * NS + 0) * NCAP_S + q] = e.x;
            q = atomicAdd(&ncur[n.y * NS + 1], 1); if (q < NCAP_S) nhedge[((size_t)n.y * NS + 1) * NCAP_S + q] = e.y;
            q = atomicAdd(&ncur[n.z * NS + 0], 1); if (q < NCAP_S) nhedge[((size_t)n.z * NS + 0) * NCAP_S + q] = e.z;
            q = atomicAdd(&ncur[n.w * NS + 1], 1); if (q < NCAP_S) nhedge[((size_t)n.w * NS + 1) * NCAP_S + q] = e.w;
        }
    } else {
        __shared__ int sidx[4][HS * HCAP_S];     // 4KB
        int b = bid - SCAT_BLOCKS;
        int w = tid >> 6, lt = tid & 63;         // wave per hyperedge, lane owns 4 channels
        int e = b * 4 + w;
        int c0 = hcur[e * HS + 0], c1 = hcur[e * HS + 1];
        int c2 = hcur[e * HS + 2], c3 = hcur[e * HS + 3];
        int degR = c0 + c1 + c2 + c3;            // true degree (reference divisor)
        int d0 = min(c0, HCAP_S), d1 = min(c1, HCAP_S);
        int d2 = min(c2, HCAP_S), d3 = min(c3, HCAP_S);
        int o1 = d0, o2 = d0 + d1, o3 = o2 + d2, degC = o3 + d3;
        const int* base = hmem + (size_t)e * HS * HCAP_S;
        // compact the 4 sub-lists into contiguous LDS (4 coalesced loads)
        if (lt < d0) sidx[w][lt]      = base[lt];
        if (lt < d1) sidx[w][o1 + lt] = base[HCAP_S + lt];
        if (lt < d2) sidx[w][o2 + lt] = base[2 * HCAP_S + lt];
        if (lt < d3) sidx[w][o3 + lt] = base[3 * HCAP_S + lt];
        __syncthreads();
        float4 ac0 = {0,0,0,0}, ac1 = {0,0,0,0}, ac2 = {0,0,0,0}, ac3 = {0,0,0,0};
        int j = 0;
        for (; j + 8 <= degC; j += 8) {          // 8 independent gathers in flight
            int4 ia = *(const int4*)&sidx[w][j];
            int4 ib = *(const int4*)&sidx[w][j + 4];
            uint2 g0 = x16[(size_t)ia.x * 64 + lt];
            uint2 g1 = x16[(size_t)ia.y * 64 + lt];
            uint2 g2 = x16[(size_t)ia.z * 64 + lt];
            uint2 g3 = x16[(size_t)ia.w * 64 + lt];
            uint2 g4 = x16[(size_t)ib.x * 64 + lt];
            uint2 g5 = x16[(size_t)ib.y * 64 + lt];
            uint2 g6 = x16[(size_t)ib.z * 64 + lt];
            uint2 g7 = x16[(size_t)ib.w * 64 + lt];
            acc4(ac0, u2tof4(g0)); acc4(ac1, u2tof4(g1));
            acc4(ac2, u2tof4(g2)); acc4(ac3, u2tof4(g3));
            acc4(ac0, u2tof4(g4)); acc4(ac1, u2tof4(g5));
            acc4(ac2, u2tof4(g6)); acc4(ac3, u2tof4(g7));
        }
        for (; j < degC; j++)
            acc4(ac0, u2tof4(x16[(size_t)sidx[w][j] * 64 + lt]));
        float sx = (ac0.x + ac1.x) + (ac2.x + ac3.x);
        float sy = (ac0.y + ac1.y) + (ac2.y + ac3.y);
        float sz = (ac0.z + ac1.z) + (ac2.z + ac3.z);
        float sw = (ac0.w + ac1.w) + (ac2.w + ac3.w);
        float inv = degR > 0 ? 1.0f / (float)degR : 0.0f;
        uint2 o; o.x = f2h(sx * inv, sy * inv); o.y = f2h(sz * inv, sw * inv);
        hx[(size_t)e * 64 + lt] = o;
    }
}

// ---------- K3: he = hx @ W16 fused with alpha = leaky_relu(<he, att>, 0.2) ----------
__global__ void k_gemm_alpha(const uint2* __restrict__ hx, const __half* __restrict__ W16,
                             const float* __restrict__ att, __half* __restrict__ he,
                             float* __restrict__ alpha) {
    __shared__ float xs[GR][KIN];
    int tid = threadIdx.x;
    int e0 = blockIdx.x * GR;
    #pragma unroll
    for (int jj = 0; jj < GR * 64 / 256; jj++) {
        int f = jj * 256 + tid;
        int r = f >> 6, k4 = f & 63;
        float4 v = u2tof4(hx[(size_t)(e0 + r) * 64 + k4]);
        *(float4*)&xs[r][k4 * 4] = v;
    }
    __syncthreads();
    float acc[GR];
    #pragma unroll
    for (int r = 0; r < GR; r++) acc[r] = 0.f;
    int c = tid;
    const __half* wp = W16 + c;
    for (int k = 0; k < KIN; k++) {
        float wv = __half2float(wp[(size_t)k * CH]);
        #pragma unroll
        for (int r = 0; r < GR; r++) acc[r] += xs[r][k] * wv;
    }
    #pragma unroll
    for (int r = 0; r < GR; r++)
        he[(size_t)(e0 + r) * CH + c] = __float2half_rn(acc[r]);
    float av = att[c];
    int lane = tid & 63, h = tid >> 6;  // wave == head (64 consecutive channels)
    #pragma unroll
    for (int r = 0; r < GR; r++) {
        float p = acc[r] * av;
        #pragma unroll
        for (int d = 32; d >= 1; d >>= 1) p += __shfl_xor(p, d, 64);
        if (lane == 0) alpha[(e0 + r) * HEADS + h] = p > 0.f ? p : 0.2f * p;
    }
}

// ---------- K4: stage2 per-node softmax + weighted gather-sum ----------
__global__ void k_stage2(const uint2* __restrict__ he, const float4* __restrict__ alpha4,
                         const int* __restrict__ ncur, const int* __restrict__ nhedge,
                         float4* __restrict__ out) {
    __shared__ int   nh[4][64];
    __shared__ float wl[4][4][64];   // [wave][head][member] -> float4-readable
    int tid = threadIdx.x;
    int w = tid >> 6, lt = tid & 63;
    int n = blockIdx.x * 4 + w;
    int c0 = ncur[n * NS + 0], c1 = ncur[n * NS + 1];
    int d0 = min(c0, NCAP_S), d1 = min(c1, NCAP_S);
    int deg = d0 + d1;
    float4 aj = make_float4(-INFINITY, -INFINITY, -INFINITY, -INFINITY);
    if (lt < deg) {
        int ej = (lt < d0) ? nhedge[((size_t)n * NS + 0) * NCAP_S + lt]
                           : nhedge[((size_t)n * NS + 1) * NCAP_S + (lt - d0)];
        nh[w][lt] = ej;
        aj = alpha4[ej];
    }
    float4 mx = aj;
    #pragma unroll
    for (int d = 32; d >= 1; d >>= 1) {
        mx.x = fmaxf(mx.x, __shfl_xor(mx.x, d, 64));
        mx.y = fmaxf(mx.y, __shfl_xor(mx.y, d, 64));
        mx.z = fmaxf(mx.z, __shfl_xor(mx.z, d, 64));
        mx.w = fmaxf(mx.w, __shfl_xor(mx.w, d, 64));
    }
    float4 w4 = make_float4(0.f, 0.f, 0.f, 0.f);
    if (lt < deg) {
        w4.x = __expf(aj.x - mx.x); w4.y = __expf(aj.y - mx.y);
        w4.z = __expf(aj.z - mx.z); w4.w = __expf(aj.w - mx.w);
        wl[w][0][lt] = w4.x; wl[w][1][lt] = w4.y;
        wl[w][2][lt] = w4.z; wl[w][3][lt] = w4.w;
    }
    float4 dn = w4;
    #pragma unroll
    for (int d = 32; d >= 1; d >>= 1) {
        dn.x += __shfl_xor(dn.x, d, 64);
        dn.y += __shfl_xor(dn.y, d, 64);
        dn.z += __shfl_xor(dn.z, d, 64);
        dn.w += __shfl_xor(dn.w, d, 64);
    }
    int h = lt >> 4;  // lane owns channels 4lt..4lt+3 -> head
    float den = h < 2 ? (h == 0 ? dn.x : dn.y) : (h == 2 ? dn.z : dn.w);
    float4 ac = make_float4(0.f, 0.f, 0.f, 0.f);
    if (deg > 0) {
        int j = 0;
        for (; j + 4 <= deg; j += 4) {
            int4 e4 = *(const int4*)&nh[w][j];
            float4 ww = *(const float4*)&wl[w][h][j];
            uint2 g0 = he[(size_t)e4.x * 64 + lt];
            uint2 g1 = he[(size_t)e4.y * 64 + lt];
            uint2 g2 = he[(size_t)e4.z * 64 + lt];
            uint2 g3 = he[(size_t)e4.w * 64 + lt];
            float4 f0 = u2tof4(g0), f1 = u2tof4(g1), f2 = u2tof4(g2), f3 = u2tof4(g3);
            ac.x += ww.x * f0.x + ww.y * f1.x; ac.x += ww.z * f2.x + ww.w * f3.x;
            ac.y += ww.x * f0.y + ww.y * f1.y; ac.y += ww.z * f2.y + ww.w * f3.y;
            ac.z += ww.x * f0.z + ww.y * f1.z; ac.z += ww.z * f2.z + ww.w * f3.z;
            ac.w += ww.x * f0.w + ww.y * f1.w; ac.w += ww.z * f2.w + ww.w * f3.w;
        }
        for (; j < deg; j++) {
            int ea = nh[w][j];
            float wa = wl[w][h][j];
            float4 fa = u2tof4(he[(size_t)ea * 64 + lt]);
            ac.x += wa * fa.x; ac.y += wa * fa.y; ac.z += wa * fa.z; ac.w += wa * fa.w;
        }
        float inv = 1.0f / den;
        ac.x *= inv; ac.y *= inv; ac.z *= inv; ac.w *= inv;
    }
    out[(size_t)n * 64 + lt] = ac;
}

extern "C" void kernel_launch(void* const* d_in, const int* in_sizes, int n_in,
                              void* d_out, int out_size, void* d_ws, size_t ws_size,
                              hipStream_t stream) {
    const float* x        = (const float*)d_in[0];
    const float* W        = (const float*)d_in[1];
    const float* att      = (const float*)d_in[2];
    const int*   node_idx = (const int*)d_in[3];
    const int*   hedge_idx= (const int*)d_in[4];
    float4* out4 = (float4*)d_out;

    char* ws = (char*)d_ws;
    size_t o = 0;
    auto alloc = [&](size_t b) { size_t r = o; o += (b + 255) & ~(size_t)255; return r; };
    uint2* hx    = (uint2*)(ws + alloc(sizeof(__half) * (size_t)N_HEDGES * KIN));     // 5.12 MB
    float* alpha = (float*)(ws + alloc(sizeof(float) * (size_t)N_HEDGES * HEADS));    // 160 KB
    int*   hcur  = (int*)(ws + alloc(sizeof(int) * (size_t)N_HEDGES * HS));           // 160 KB
    int*   ncur  = (int*)(ws + alloc(sizeof(int) * (size_t)N_NODES * NS));            // 400 KB
    uint2* W16   = (uint2*)(ws + alloc(sizeof(__half) * (size_t)KIN * CH));           // 128 KB
    // hmem sub-lists are dead after stage1; he (gemm output, 5.12MB) reuses the region
    size_t hmem_off = alloc(sizeof(int) * (size_t)N_HEDGES * HS * HCAP_S);            // 10.24 MB
    int*    hmem = (int*)(ws + hmem_off);
    __half* he   = (__half*)(ws + hmem_off);
    int*   nhedge = (int*)(ws + alloc(sizeof(int) * (size_t)N_NODES * NS * NCAP_S));  // 12.8 MB
    // x16 lives in d_out (51.2 MB): written by K1, read by K2, overwritten by K4
    uint2* x16 = (uint2*)d_out;

    hipMemsetAsync(hcur, 0, sizeof(int) * (size_t)N_HEDGES * HS, stream);
    hipMemsetAsync(ncur, 0, sizeof(int) * (size_t)N_NODES * NS, stream);
    k_hscatter_cvt<<<SCAT_BLOCKS + CVT_BLOCKS + WCVT_BLOCKS, 256, 0, stream>>>(
        (const int4*)node_idx, (const int4*)hedge_idx, hcur, hmem,
        (const float4*)x, x16, (const float4*)W, W16);
    k_nscatter_stage1<<<SCAT_BLOCKS + S1_BLOCKS, 256, 0, stream>>>(
        (const int4*)node_idx, (const int4*)hedge_idx, ncur, nhedge, hcur, hmem, x16, hx);
    k_gemm_alpha<<<N_HEDGES / GR, 256, 0, stream>>>(hx, (const __half*)W16, att, he, alpha);
    k_stage2<<<N_NODES / 4, 256, 0, stream>>>((const uint2*)he, (const float4*)alpha,
                                              ncur, nhedge, out4);
}